// Round 7
// baseline (74.313 us; speedup 1.0000x reference)
//
#include <hip/hip_runtime.h>
#include <math.h>

#define BB 8
#define HH 256
#define WW 256
#define SW 8                 // strip width (columns per block)
#define NBLK (BB*32)         // 256 blocks: 8 images x 32 strips -> 1 block/CU
#define NT 512
#define EPSF 1e-6f
#define MSTRIDE 68           // maskb row stride (bytes)
#define GSTRIDE 20           // gbuf row stride (bytes)
#define POISON 0xAAAAAAAAu

// ws layout: float part[1024] (256 blocks x 4) at 0;
// u32 tickets at u32-index 1024 + img*16 (64B apart), global ticket at 1024+128.
// Tickets are CAS-initialized from the harness's 0xAA poison (or 0) each call.

__device__ __forceinline__ int nearest_dist(const unsigned long long* m, int c)
{
    const int w = c >> 6, o = c & 63;
    int dr = 256;
    const unsigned long long right = m[w] >> o;       // bit o -> pos 0
    if (right) dr = __builtin_ctzll(right);
    else {
        for (int ww = w + 1; ww < 4; ++ww)
            if (m[ww]) { dr = (ww - w) * 64 - o + __builtin_ctzll(m[ww]); break; }
    }
    int dl = 256;
    const unsigned long long left = m[w] << (63 - o); // bit o -> pos 63
    if (left) dl = __builtin_clzll(left);
    else {
        for (int ww = w - 1; ww >= 0; --ww)
            if (m[ww]) { dl = o + 1 + (w - ww - 1) * 64 + __builtin_clzll(m[ww]); break; }
    }
    const int n = dr < dl ? dr : dl;
    return n < 255 ? n : 255;
}

__global__ __launch_bounds__(NT) void k_fused(
    const float* __restrict__ pred, const float* __restrict__ target,
    const int* __restrict__ from_logits, float* __restrict__ ws,
    float* __restrict__ out)
{
    __shared__ unsigned char maskb[HH * MSTRIDE];
    __shared__ unsigned char gbuf[HH * GSTRIDE];
    __shared__ float red[32];
    __shared__ float fin[16];
    __shared__ int amLast;

    const int blk = blockIdx.x;
    const int b   = blk >> 5;            // image
    const int c0  = (blk & 31) * SW;     // first owned column
    const int t   = threadIdx.x;
    const int fl  = *from_logits;
    const float* tb = target + b * HH * WW;
    const float* pb = pred   + b * HH * WW;

    // ---- phase 0: full-image nibble mask (coalesced float4, L2-resident) ----
    {
        const float4* t4 = (const float4*)tb;
        #pragma unroll 4
        for (int i = 0; i < 32; ++i) {
            const int f = i * NT + t;
            const float4 v = t4[f];
            const int row = f >> 6;
            const int q   = f & 63;
            const unsigned nib = (v.x > 0.5f ? 1u : 0u) | (v.y > 0.5f ? 2u : 0u)
                               | (v.z > 0.5f ? 4u : 0u) | (v.w > 0.5f ? 8u : 0u);
            maskb[row * MSTRIDE + q] = (unsigned char)nib;
        }
    }
    __syncthreads();

    // ---- phase A: exact row DT at owned columns via 256-bit bit-scan ----
    {
        const int row = t >> 1;
        const int k0  = (t & 1) * 4;
        const unsigned char* mb = maskb + row * MSTRIDE;
        unsigned long long m[4];
        #pragma unroll
        for (int w = 0; w < 4; ++w) {
            unsigned long long acc = 0ull;
            #pragma unroll
            for (int j = 0; j < 4; ++j) {
                unsigned x = *(const unsigned*)(mb + (w * 4 + j) * 4);
                x = (x | (x >> 4)) & 0x00FF00FFu;
                x = (x | (x >> 8)) & 0x0000FFFFu;
                acc |= ((unsigned long long)x) << (16 * j);
            }
            m[w] = acc;
        }
        const unsigned long long mi[4] = { ~m[0], ~m[1], ~m[2], ~m[3] };
        unsigned lo = 0, hi = 0;
        #pragma unroll
        for (int j = 0; j < 4; ++j) {
            const int c  = c0 + k0 + j;
            const unsigned n1 = (unsigned)nearest_dist(m,  c);
            const unsigned n0 = (unsigned)nearest_dist(mi, c);
            const unsigned pv = n1 | (n0 << 8);
            if (j < 2) lo |= pv << (16 * j);
            else       hi |= pv << (16 * (j - 2));
        }
        *(unsigned*)(gbuf + row * GSTRIDE + k0 * 2)     = lo;
        *(unsigned*)(gbuf + row * GSTRIDE + k0 * 2 + 4) = hi;
    }
    __syncthreads();

    // ---- phase B: column DT (early-exit LDS scan) + dice + boundary ----
    float s_pt = 0.0f, s_p2 = 0.0f, s_st = 0.0f, s_bd = 0.0f;
    {
        const int k  = t & 7;
        const int c  = c0 + k;
        const int r0 = (t >> 3) * 4;
        float pv[4];
        #pragma unroll
        for (int rr = 0; rr < 4; ++rr) pv[rr] = pb[(r0 + rr) * WW + c];

        #pragma unroll 2
        for (int rr = 0; rr < 4; ++rr) {
            const int r = r0 + rr;
            const float p  = pv[rr];
            const float sp = fl ? (1.0f / (1.0f + __expf(-p))) : p;
            const unsigned short vc = *(const unsigned short*)(gbuf + r * GSTRIDE + 2 * k);
            const int n1 = vc & 255, n0 = vc >> 8;
            int best1 = n1 * n1, best0 = n0 * n0;
            for (int d = 1;; ++d) {
                const int dd = d * d;
                if (dd >= best1 && dd >= best0) break;
                const int u = r - d, v2 = r + d;
                if (u >= 0) {
                    const unsigned short vu = *(const unsigned short*)(gbuf + u * GSTRIDE + 2 * k);
                    const int a = vu & 255, bq = vu >> 8;
                    best1 = min(best1, a * a + dd);
                    best0 = min(best0, bq * bq + dd);
                }
                if (v2 < HH) {
                    const unsigned short vd = *(const unsigned short*)(gbuf + v2 * GSTRIDE + 2 * k);
                    const int a = vd & 255, bq = vd >> 8;
                    best1 = min(best1, a * a + dd);
                    best0 = min(best0, bq * bq + dd);
                }
            }
            const float dist = sqrtf((float)best1) + sqrtf((float)best0);
            const int bit = (maskb[r * MSTRIDE + (c >> 2)] >> (c & 3)) & 1;
            const float tv = (float)bit;
            s_pt += sp * tv;
            s_p2 += sp * sp;
            s_st += tv;
            s_bd += sp * dist;
        }
    }

    // ---- block reduction -> 4 partials ----
    #pragma unroll
    for (int o = 32; o > 0; o >>= 1) {
        s_pt += __shfl_down(s_pt, o);
        s_p2 += __shfl_down(s_p2, o);
        s_st += __shfl_down(s_st, o);
        s_bd += __shfl_down(s_bd, o);
    }
    const int lane = t & 63, wid = t >> 6;
    if (lane == 0) {
        red[wid] = s_pt; red[8 + wid] = s_p2;
        red[16 + wid] = s_st; red[24 + wid] = s_bd;
    }
    __syncthreads();

    // ---- ticket cascade (t==0): per-image line, then global line ----
    if (t == 0) {
        float a = 0, b2 = 0, cc = 0, dd = 0;
        #pragma unroll
        for (int w = 0; w < 8; ++w) {
            a  += red[w];      b2 += red[8 + w];
            cc += red[16 + w]; dd += red[24 + w];
        }
        ws[blk * 4 + 0] = a;  ws[blk * 4 + 1] = b2;
        ws[blk * 4 + 2] = cc; ws[blk * 4 + 3] = dd;
        __threadfence();
        unsigned* tick = (unsigned*)ws + 1024;
        unsigned* it = tick + b * 16;            // 64B apart per image
        atomicCAS(it, POISON, 0u);               // idempotent poison-init
        const unsigned io = atomicAdd(it, 1u);
        int last_all = 0;
        if (io == 31u) {
            unsigned* gt = tick + 128;
            atomicCAS(gt, POISON, 0u);
            const unsigned go = atomicAdd(gt, 1u);
            last_all = (go == 7u);
        }
        amLast = last_all;
    }
    __syncthreads();
    if (!amLast) return;
    __threadfence();

    // ---- final reduction (global-last block only; 512 threads = 8 waves) ----
    {
        volatile const float* vp = (volatile const float*)ws;  // bypass stale L1
        const int img = t >> 6;                 // one wave per image
        const int j   = t & 63;
        float pt = 0, p2 = 0, st = 0, bd = 0;
        if (j < 32) {                           // strip j of image img
            const int idx = (img * 32 + j) * 4;
            pt = vp[idx + 0]; p2 = vp[idx + 1];
            st = vp[idx + 2]; bd = vp[idx + 3];
        }
        #pragma unroll
        for (int o = 32; o > 0; o >>= 1) {
            pt += __shfl_down(pt, o);
            p2 += __shfl_down(p2, o);
            st += __shfl_down(st, o);
            bd += __shfl_down(bd, o);
        }
        if (j == 0) {
            fin[img]     = 1.0f - (2.0f * pt + EPSF) / (p2 + st + EPSF);
            fin[8 + img] = bd;
        }
    }
    __syncthreads();
    if (t == 0) {
        float dice = 0, bdv = 0;
        #pragma unroll
        for (int i = 0; i < 8; ++i) { dice += fin[i]; bdv += fin[8 + i]; }
        out[0] = dice / (float)BB + bdv / (float)(BB * HH * WW);
    }
}

extern "C" void kernel_launch(void* const* d_in, const int* in_sizes, int n_in,
                              void* d_out, int out_size, void* d_ws, size_t ws_size,
                              hipStream_t stream) {
    const float* pred   = (const float*)d_in[0];
    const float* target = (const float*)d_in[1];
    const int*   fl     = (const int*)d_in[2];
    float* out = (float*)d_out;
    float* ws  = (float*)d_ws;

    k_fused<<<NBLK, NT, 0, stream>>>(pred, target, fl, ws, out);
}

// Round 8
// 67.518 us; speedup vs baseline: 1.1006x; 1.1006x over previous
//
#include <hip/hip_runtime.h>
#include <math.h>

#define BB 8
#define HH 256
#define WW 256
#define SW 8                 // strip width (columns per block)
#define NBLK (BB*32)         // 256 blocks -> 1 block/CU
#define NT 512
#define EPSF 1e-6f
#define MSTRIDE 68           // maskb row stride (bytes): 64 data + 4 pad
#define GSTRIDE 24           // gbuf row stride (bytes): 16 data + 8 pad (8B-aligned quads)

// Distance (pixels) from column c to nearest set bit of the 256-bit row mask
// m[4], capped at 255 (255 only stands in for "row empty", prob ~2^-256 here).
__device__ __forceinline__ int nearest_dist(const unsigned long long* m, int c)
{
    const int w = c >> 6, o = c & 63;
    int dr = 256;
    const unsigned long long right = m[w] >> o;       // bit o -> pos 0
    if (right) dr = __builtin_ctzll(right);
    else {
        for (int ww = w + 1; ww < 4; ++ww)
            if (m[ww]) { dr = (ww - w) * 64 - o + __builtin_ctzll(m[ww]); break; }
    }
    int dl = 256;
    const unsigned long long left = m[w] << (63 - o); // bit o -> pos 63
    if (left) dl = __builtin_clzll(left);
    else {
        for (int ww = w - 1; ww >= 0; --ww)
            if (m[ww]) { dl = o + 1 + (w - ww - 1) * 64 + __builtin_clzll(m[ww]); break; }
    }
    const int n = dr < dl ? dr : dl;
    return n < 255 ? n : 255;
}

__global__ __launch_bounds__(NT) void k_fused(
    const float* __restrict__ pred, const float* __restrict__ target,
    const int* __restrict__ from_logits, float* __restrict__ part)
{
    __shared__ __align__(16) unsigned char maskb[HH * MSTRIDE];
    __shared__ __align__(16) unsigned char gbuf[HH * GSTRIDE];
    __shared__ float red[32];

    const int blk = blockIdx.x;
    const int b   = blk & 7;             // image == XCD (round-robin dispatch)
    const int c0  = (blk >> 3) * SW;     // first owned column
    const int t   = threadIdx.x;
    const int fl  = *from_logits;
    const float* tb = target + b * HH * WW;
    const float* pb = pred   + b * HH * WW;

    // ---- phase 0: full-image nibble mask (coalesced float4, XCD-L2 resident) ----
    {
        const float4* t4 = (const float4*)tb;
        #pragma unroll 4
        for (int i = 0; i < 32; ++i) {
            const int f = i * NT + t;          // float4 index, 16384 total
            const float4 v = t4[f];
            const int row = f >> 6;
            const int q   = f & 63;
            const unsigned nib = (v.x > 0.5f ? 1u : 0u) | (v.y > 0.5f ? 2u : 0u)
                               | (v.z > 0.5f ? 4u : 0u) | (v.w > 0.5f ? 8u : 0u);
            maskb[row * MSTRIDE + q] = (unsigned char)nib;
        }
    }
    __syncthreads();

    // ---- phase A: exact row DT at owned columns via 256-bit bit-scan ----
    {
        const int row = t >> 1;                // 2 threads per row
        const int k0  = (t & 1) * 4;           // 4 owned columns each
        const unsigned char* mb = maskb + row * MSTRIDE;
        unsigned long long m[4];
        #pragma unroll
        for (int w = 0; w < 4; ++w) {
            unsigned long long acc = 0ull;
            #pragma unroll
            for (int j = 0; j < 4; ++j) {
                unsigned x = *(const unsigned*)(mb + (w * 4 + j) * 4);
                x = (x | (x >> 4)) & 0x00FF00FFu;   // nibble-compress to 8 bits
                x = (x | (x >> 8)) & 0x0000FFFFu;
                acc |= ((unsigned long long)x) << (16 * j);
            }
            m[w] = acc;
        }
        const unsigned long long mi[4] = { ~m[0], ~m[1], ~m[2], ~m[3] };
        unsigned lo = 0, hi = 0;
        #pragma unroll
        for (int j = 0; j < 4; ++j) {
            const int c  = c0 + k0 + j;
            const unsigned n1 = (unsigned)nearest_dist(m,  c);
            const unsigned n0 = (unsigned)nearest_dist(mi, c);
            const unsigned pv = n1 | (n0 << 8);
            if (j < 2) lo |= pv << (16 * j);
            else       hi |= pv << (16 * (j - 2));
        }
        *(unsigned*)(gbuf + row * GSTRIDE + k0 * 2)     = lo;
        *(unsigned*)(gbuf + row * GSTRIDE + k0 * 2 + 4) = hi;
    }
    __syncthreads();

    // ---- phase B: column DT, 4 adjacent columns per thread (one row each);
    //      each LDS probe (uint2, 8B-aligned) serves all 4 columns ----
    float s_pt = 0.0f, s_p2 = 0.0f, s_st = 0.0f, s_bd = 0.0f;
    {
        const int r = t >> 1;                  // owned row
        const int q = t & 1;                   // column quad within strip
        const float4 p4 = *(const float4*)&pb[r * WW + c0 + 4 * q];
        float sp[4];
        sp[0] = fl ? (1.0f / (1.0f + __expf(-p4.x))) : p4.x;
        sp[1] = fl ? (1.0f / (1.0f + __expf(-p4.y))) : p4.y;
        sp[2] = fl ? (1.0f / (1.0f + __expf(-p4.z))) : p4.z;
        sp[3] = fl ? (1.0f / (1.0f + __expf(-p4.w))) : p4.w;

        const uint2 vc = *(const uint2*)(gbuf + r * GSTRIDE + 8 * q);
        int b1[4], b0[4];
        {
            const unsigned w0 = vc.x, w1 = vc.y;
            const int n10 = w0 & 255,        n00 = (w0 >> 8) & 255;
            const int n11 = (w0 >> 16) & 255, n01 = (w0 >> 24) & 255;
            const int n12 = w1 & 255,        n02 = (w1 >> 8) & 255;
            const int n13 = (w1 >> 16) & 255, n03 = (w1 >> 24) & 255;
            b1[0] = n10 * n10; b0[0] = n00 * n00;
            b1[1] = n11 * n11; b0[1] = n01 * n01;
            b1[2] = n12 * n12; b0[2] = n02 * n02;
            b1[3] = n13 * n13; b0[3] = n03 * n03;
        }
        for (int d = 1;; ++d) {
            const int dd = d * d;
            int mx = b1[0];
            #pragma unroll
            for (int j = 0; j < 4; ++j) { mx = max(mx, b1[j]); mx = max(mx, b0[j]); }
            if (dd >= mx) break;
            const int u = r - d, v2 = r + d;
            if (u >= 0) {
                const uint2 vu = *(const uint2*)(gbuf + u * GSTRIDE + 8 * q);
                const unsigned w0 = vu.x, w1 = vu.y;
                const int a0 = w0 & 255, c0b = (w0 >> 8) & 255;
                const int a1 = (w0 >> 16) & 255, c1b = (w0 >> 24) & 255;
                const int a2 = w1 & 255, c2b = (w1 >> 8) & 255;
                const int a3 = (w1 >> 16) & 255, c3b = (w1 >> 24) & 255;
                b1[0] = min(b1[0], a0 * a0 + dd); b0[0] = min(b0[0], c0b * c0b + dd);
                b1[1] = min(b1[1], a1 * a1 + dd); b0[1] = min(b0[1], c1b * c1b + dd);
                b1[2] = min(b1[2], a2 * a2 + dd); b0[2] = min(b0[2], c2b * c2b + dd);
                b1[3] = min(b1[3], a3 * a3 + dd); b0[3] = min(b0[3], c3b * c3b + dd);
            }
            if (v2 < HH) {
                const uint2 vd = *(const uint2*)(gbuf + v2 * GSTRIDE + 8 * q);
                const unsigned w0 = vd.x, w1 = vd.y;
                const int a0 = w0 & 255, c0b = (w0 >> 8) & 255;
                const int a1 = (w0 >> 16) & 255, c1b = (w0 >> 24) & 255;
                const int a2 = w1 & 255, c2b = (w1 >> 8) & 255;
                const int a3 = (w1 >> 16) & 255, c3b = (w1 >> 24) & 255;
                b1[0] = min(b1[0], a0 * a0 + dd); b0[0] = min(b0[0], c0b * c0b + dd);
                b1[1] = min(b1[1], a1 * a1 + dd); b0[1] = min(b0[1], c1b * c1b + dd);
                b1[2] = min(b1[2], a2 * a2 + dd); b0[2] = min(b0[2], c2b * c2b + dd);
                b1[3] = min(b1[3], a3 * a3 + dd); b0[3] = min(b0[3], c3b * c3b + dd);
            }
        }
        // target bits for the 4 owned columns = one nibble byte
        const unsigned nib = maskb[r * MSTRIDE + (c0 >> 2) + q];
        #pragma unroll
        for (int j = 0; j < 4; ++j) {
            const float dist = sqrtf((float)b1[j]) + sqrtf((float)b0[j]);
            const float tv = (float)((nib >> j) & 1);
            s_pt += sp[j] * tv;
            s_p2 += sp[j] * sp[j];
            s_st += tv;                        // t^2 == t (binary)
            s_bd += sp[j] * dist;
        }
    }

    // ---- block reduction -> 4 partials per block ----
    #pragma unroll
    for (int o = 32; o > 0; o >>= 1) {
        s_pt += __shfl_down(s_pt, o);
        s_p2 += __shfl_down(s_p2, o);
        s_st += __shfl_down(s_st, o);
        s_bd += __shfl_down(s_bd, o);
    }
    const int lane = t & 63, wid = t >> 6;     // 8 waves
    if (lane == 0) {
        red[wid] = s_pt; red[8 + wid] = s_p2;
        red[16 + wid] = s_st; red[24 + wid] = s_bd;
    }
    __syncthreads();
    if (t == 0) {
        float a = 0, b2 = 0, cc = 0, dd = 0;
        #pragma unroll
        for (int w = 0; w < 8; ++w) {
            a  += red[w];      b2 += red[8 + w];
            cc += red[16 + w]; dd += red[24 + w];
        }
        part[blk * 4 + 0] = a;  part[blk * 4 + 1] = b2;
        part[blk * 4 + 2] = cc; part[blk * 4 + 3] = dd;
    }
}

__global__ __launch_bounds__(64) void k_final(
    const float* __restrict__ part, float* __restrict__ out)
{
    const int t = threadIdx.x;                 // 64 = 8 images x 8 lanes
    const int b = t >> 3, j = t & 7;
    float pt = 0, p2 = 0, st = 0, bd = 0;
    #pragma unroll
    for (int s = j; s < 32; s += 8) {          // strip s of image b: blk = b + 8*s
        const int idx = (b + 8 * s) * 4;
        pt += part[idx + 0]; p2 += part[idx + 1];
        st += part[idx + 2]; bd += part[idx + 3];
    }
    #pragma unroll
    for (int o = 4; o > 0; o >>= 1) {          // reduce 8 lanes per image
        pt += __shfl_down(pt, o, 8);
        p2 += __shfl_down(p2, o, 8);
        st += __shfl_down(st, o, 8);
        bd += __shfl_down(bd, o, 8);
    }
    float dice = (j == 0) ? (1.0f - (2.0f * pt + EPSF) / (p2 + st + EPSF)) : 0.0f;
    float bdv  = (j == 0) ? bd : 0.0f;
    #pragma unroll
    for (int o = 8; o < 64; o <<= 1) {         // reduce across images
        dice += __shfl_down(dice, o);
        bdv  += __shfl_down(bdv, o);
    }
    if (t == 0)
        out[0] = dice / (float)BB + bdv / (float)(BB * HH * WW);
}

extern "C" void kernel_launch(void* const* d_in, const int* in_sizes, int n_in,
                              void* d_out, int out_size, void* d_ws, size_t ws_size,
                              hipStream_t stream) {
    const float* pred   = (const float*)d_in[0];
    const float* target = (const float*)d_in[1];
    const int*   fl     = (const int*)d_in[2];
    float* out  = (float*)d_out;
    float* part = (float*)d_ws;                // 256*4 floats, fully overwritten

    k_fused<<<NBLK, NT, 0, stream>>>(pred, target, fl, part);
    k_final<<<1, 64, 0, stream>>>(part, out);
}

// Round 9
// 66.657 us; speedup vs baseline: 1.1149x; 1.0129x over previous
//
#include <hip/hip_runtime.h>
#include <math.h>

#define BB 8
#define HH 256
#define WW 256
#define SW 8                 // strip width (columns per block)
#define NBLK (BB*32)         // 256 blocks -> 1 block/CU
#define NT 512
#define EPSF 1e-6f
#define MSTRIDE 68           // maskb row stride (bytes): 64 data + 4 pad (17 words)
#define GSTRIDE 20           // gbuf row stride (bytes): 16 data + 4 pad (5 words, odd -> 2-way banks)

// Distance (pixels) from column c to nearest set bit of the 256-bit row mask
// m[4], capped at 255 (255 only stands in for "row empty", prob ~2^-256 here).
__device__ __forceinline__ int nearest_dist(const unsigned long long* m, int c)
{
    const int w = c >> 6, o = c & 63;
    int dr = 256;
    const unsigned long long right = m[w] >> o;       // bit o -> pos 0
    if (right) dr = __builtin_ctzll(right);
    else {
        for (int ww = w + 1; ww < 4; ++ww)
            if (m[ww]) { dr = (ww - w) * 64 - o + __builtin_ctzll(m[ww]); break; }
    }
    int dl = 256;
    const unsigned long long left = m[w] << (63 - o); // bit o -> pos 63
    if (left) dl = __builtin_clzll(left);
    else {
        for (int ww = w - 1; ww >= 0; --ww)
            if (m[ww]) { dl = o + 1 + (w - ww - 1) * 64 + __builtin_clzll(m[ww]); break; }
    }
    const int n = dr < dl ? dr : dl;
    return n < 255 ? n : 255;
}

__global__ __launch_bounds__(NT) void k_fused(
    const float* __restrict__ pred, const float* __restrict__ target,
    const int* __restrict__ from_logits, float* __restrict__ part)
{
    __shared__ __align__(16) unsigned char maskb[HH * MSTRIDE];
    __shared__ __align__(16) unsigned char gbuf[HH * GSTRIDE];
    __shared__ float red[32];

    const int blk = blockIdx.x;
    const int b   = blk & 7;             // image == XCD (round-robin dispatch)
    const int c0  = (blk >> 3) * SW;     // first owned column
    const int t   = threadIdx.x;
    const float* tb = target + b * HH * WW;
    const float* pb = pred   + b * HH * WW;

    // thread's phase-A/B identity: one row, one 4-column quad
    const int row  = t >> 1;
    const int half = t & 1;

    // ---- hoisted loads: overlap their latency with phases 0/A ----
    const float4 p4 = *(const float4*)&pb[row * WW + c0 + 4 * half];
    const int fl = *from_logits;

    // ---- phase 0: full-image nibble mask (coalesced float4, XCD-L2 resident) ----
    {
        const float4* t4 = (const float4*)tb;
        #pragma unroll 4
        for (int i = 0; i < 32; ++i) {
            const int f = i * NT + t;          // float4 index, 16384 total
            const float4 v = t4[f];
            const int rr = f >> 6;
            const int q  = f & 63;
            const unsigned nib = (v.x > 0.5f ? 1u : 0u) | (v.y > 0.5f ? 2u : 0u)
                               | (v.z > 0.5f ? 4u : 0u) | (v.w > 0.5f ? 8u : 0u);
            maskb[rr * MSTRIDE + q] = (unsigned char)nib;
        }
    }
    __syncthreads();

    // ---- phase A: exact row DT at owned columns via 256-bit bit-scan.
    //      Split build: each of the row's 2 threads builds half the mask
    //      (8 LDS reads), halves exchanged via 64-bit shuffles. ----
    {
        const unsigned char* mb = maskb + row * MSTRIDE;
        unsigned long long mA, mB;             // my words (half*2, half*2+1)
        #pragma unroll
        for (int wi = 0; wi < 2; ++wi) {
            const int w = half * 2 + wi;
            unsigned long long acc = 0ull;
            #pragma unroll
            for (int j = 0; j < 4; ++j) {
                unsigned x = *(const unsigned*)(mb + (w * 4 + j) * 4);
                x = (x | (x >> 4)) & 0x00FF00FFu;   // nibble-compress to 8 bits
                x = (x | (x >> 8)) & 0x0000FFFFu;
                acc |= ((unsigned long long)x) << (16 * j);
            }
            if (wi == 0) mA = acc; else mB = acc;
        }
        const unsigned long long pA = __shfl_xor(mA, 1);
        const unsigned long long pB = __shfl_xor(mB, 1);
        unsigned long long m[4];
        if (half == 0) { m[0] = mA; m[1] = mB; m[2] = pA; m[3] = pB; }
        else           { m[0] = pA; m[1] = pB; m[2] = mA; m[3] = mB; }

        const unsigned long long mi[4] = { ~m[0], ~m[1], ~m[2], ~m[3] };
        const int k0 = half * 4;
        unsigned lo = 0, hi = 0;
        #pragma unroll
        for (int j = 0; j < 4; ++j) {
            const int c  = c0 + k0 + j;
            const unsigned n1 = (unsigned)nearest_dist(m,  c);
            const unsigned n0 = (unsigned)nearest_dist(mi, c);
            const unsigned pv = n1 | (n0 << 8);
            if (j < 2) lo |= pv << (16 * j);
            else       hi |= pv << (16 * (j - 2));
        }
        *(unsigned*)(gbuf + row * GSTRIDE + k0 * 2)     = lo;
        *(unsigned*)(gbuf + row * GSTRIDE + k0 * 2 + 4) = hi;
    }
    __syncthreads();

    // ---- phase B: column DT, 4 adjacent columns per thread (one row each);
    //      each probe = two u32 LDS reads (bank-free with odd word stride) ----
    float s_pt = 0.0f, s_p2 = 0.0f, s_st = 0.0f, s_bd = 0.0f;
    {
        const int r = row, q = half;
        float sp[4];
        sp[0] = fl ? (1.0f / (1.0f + __expf(-p4.x))) : p4.x;
        sp[1] = fl ? (1.0f / (1.0f + __expf(-p4.y))) : p4.y;
        sp[2] = fl ? (1.0f / (1.0f + __expf(-p4.z))) : p4.z;
        sp[3] = fl ? (1.0f / (1.0f + __expf(-p4.w))) : p4.w;

        const int off = r * GSTRIDE + 8 * q;
        int b1[4], b0[4];
        {
            const unsigned w0 = *(const unsigned*)(gbuf + off);
            const unsigned w1 = *(const unsigned*)(gbuf + off + 4);
            const int n10 = w0 & 255,         n00 = (w0 >> 8) & 255;
            const int n11 = (w0 >> 16) & 255, n01 = (w0 >> 24) & 255;
            const int n12 = w1 & 255,         n02 = (w1 >> 8) & 255;
            const int n13 = (w1 >> 16) & 255, n03 = (w1 >> 24) & 255;
            b1[0] = n10 * n10; b0[0] = n00 * n00;
            b1[1] = n11 * n11; b0[1] = n01 * n01;
            b1[2] = n12 * n12; b0[2] = n02 * n02;
            b1[3] = n13 * n13; b0[3] = n03 * n03;
        }
        for (int d = 1;; ++d) {
            const int dd = d * d;
            int mx = b1[0];
            #pragma unroll
            for (int j = 0; j < 4; ++j) { mx = max(mx, b1[j]); mx = max(mx, b0[j]); }
            if (dd >= mx) break;
            const int u = r - d, v2 = r + d;
            if (u >= 0) {
                const int uo = u * GSTRIDE + 8 * q;
                const unsigned w0 = *(const unsigned*)(gbuf + uo);
                const unsigned w1 = *(const unsigned*)(gbuf + uo + 4);
                const int a0 = w0 & 255,         e0 = (w0 >> 8) & 255;
                const int a1 = (w0 >> 16) & 255, e1 = (w0 >> 24) & 255;
                const int a2 = w1 & 255,         e2 = (w1 >> 8) & 255;
                const int a3 = (w1 >> 16) & 255, e3 = (w1 >> 24) & 255;
                b1[0] = min(b1[0], a0 * a0 + dd); b0[0] = min(b0[0], e0 * e0 + dd);
                b1[1] = min(b1[1], a1 * a1 + dd); b0[1] = min(b0[1], e1 * e1 + dd);
                b1[2] = min(b1[2], a2 * a2 + dd); b0[2] = min(b0[2], e2 * e2 + dd);
                b1[3] = min(b1[3], a3 * a3 + dd); b0[3] = min(b0[3], e3 * e3 + dd);
            }
            if (v2 < HH) {
                const int vo = v2 * GSTRIDE + 8 * q;
                const unsigned w0 = *(const unsigned*)(gbuf + vo);
                const unsigned w1 = *(const unsigned*)(gbuf + vo + 4);
                const int a0 = w0 & 255,         e0 = (w0 >> 8) & 255;
                const int a1 = (w0 >> 16) & 255, e1 = (w0 >> 24) & 255;
                const int a2 = w1 & 255,         e2 = (w1 >> 8) & 255;
                const int a3 = (w1 >> 16) & 255, e3 = (w1 >> 24) & 255;
                b1[0] = min(b1[0], a0 * a0 + dd); b0[0] = min(b0[0], e0 * e0 + dd);
                b1[1] = min(b1[1], a1 * a1 + dd); b0[1] = min(b0[1], e1 * e1 + dd);
                b1[2] = min(b1[2], a2 * a2 + dd); b0[2] = min(b0[2], e2 * e2 + dd);
                b1[3] = min(b1[3], a3 * a3 + dd); b0[3] = min(b0[3], e3 * e3 + dd);
            }
        }
        // target bits for the 4 owned columns = one nibble byte
        const unsigned nib = maskb[r * MSTRIDE + (c0 >> 2) + q];
        #pragma unroll
        for (int j = 0; j < 4; ++j) {
            const float dist = sqrtf((float)b1[j]) + sqrtf((float)b0[j]);
            const float tv = (float)((nib >> j) & 1);
            s_pt += sp[j] * tv;
            s_p2 += sp[j] * sp[j];
            s_st += tv;                        // t^2 == t (binary)
            s_bd += sp[j] * dist;
        }
    }

    // ---- block reduction -> 4 partials per block ----
    #pragma unroll
    for (int o = 32; o > 0; o >>= 1) {
        s_pt += __shfl_down(s_pt, o);
        s_p2 += __shfl_down(s_p2, o);
        s_st += __shfl_down(s_st, o);
        s_bd += __shfl_down(s_bd, o);
    }
    const int lane = t & 63, wid = t >> 6;     // 8 waves
    if (lane == 0) {
        red[wid] = s_pt; red[8 + wid] = s_p2;
        red[16 + wid] = s_st; red[24 + wid] = s_bd;
    }
    __syncthreads();
    if (t == 0) {
        float a = 0, b2 = 0, cc = 0, dd = 0;
        #pragma unroll
        for (int w = 0; w < 8; ++w) {
            a  += red[w];      b2 += red[8 + w];
            cc += red[16 + w]; dd += red[24 + w];
        }
        part[blk * 4 + 0] = a;  part[blk * 4 + 1] = b2;
        part[blk * 4 + 2] = cc; part[blk * 4 + 3] = dd;
    }
}

__global__ __launch_bounds__(64) void k_final(
    const float* __restrict__ part, float* __restrict__ out)
{
    const int t = threadIdx.x;                 // 64 = 8 images x 8 lanes
    const int b = t >> 3, j = t & 7;
    float pt = 0, p2 = 0, st = 0, bd = 0;
    #pragma unroll
    for (int s = j; s < 32; s += 8) {          // strip s of image b: blk = b + 8*s
        const int idx = (b + 8 * s) * 4;
        pt += part[idx + 0]; p2 += part[idx + 1];
        st += part[idx + 2]; bd += part[idx + 3];
    }
    #pragma unroll
    for (int o = 4; o > 0; o >>= 1) {          // reduce 8 lanes per image
        pt += __shfl_down(pt, o, 8);
        p2 += __shfl_down(p2, o, 8);
        st += __shfl_down(st, o, 8);
        bd += __shfl_down(bd, o, 8);
    }
    float dice = (j == 0) ? (1.0f - (2.0f * pt + EPSF) / (p2 + st + EPSF)) : 0.0f;
    float bdv  = (j == 0) ? bd : 0.0f;
    #pragma unroll
    for (int o = 8; o < 64; o <<= 1) {         // reduce across images
        dice += __shfl_down(dice, o);
        bdv  += __shfl_down(bdv, o);
    }
    if (t == 0)
        out[0] = dice / (float)BB + bdv / (float)(BB * HH * WW);
}

extern "C" void kernel_launch(void* const* d_in, const int* in_sizes, int n_in,
                              void* d_out, int out_size, void* d_ws, size_t ws_size,
                              hipStream_t stream) {
    const float* pred   = (const float*)d_in[0];
    const float* target = (const float*)d_in[1];
    const int*   fl     = (const int*)d_in[2];
    float* out  = (float*)d_out;
    float* part = (float*)d_ws;                // 256*4 floats, fully overwritten

    k_fused<<<NBLK, NT, 0, stream>>>(pred, target, fl, part);
    k_final<<<1, 64, 0, stream>>>(part, out);
}